// Round 8
// baseline (695.539 us; speedup 1.0000x reference)
//
#include <hip/hip_runtime.h>

#define SEQ_LEN 96
#define PRED_LEN 16
#define HIDDEN 64
#define FEAT 7
#define BATCH 512
#define TL (SEQ_LEN + PRED_LEN)   // 112-row sliding timeline
#define XSTR 8                    // padded row stride

typedef float v2f __attribute__((ext_vector_type(2)));

#define L2E 1.4426950408889634f

// DPP quad ops (pure VALU). HW-verified rounds 4-7.
__device__ __forceinline__ float qp_xor1(float v) {
    return __int_as_float(__builtin_amdgcn_mov_dpp(__float_as_int(v), 0xB1, 0xF, 0xF, true));
}
__device__ __forceinline__ float qp_xor2(float v) {
    return __int_as_float(__builtin_amdgcn_mov_dpp(__float_as_int(v), 0x4E, 0xF, 0xF, true));
}
template <int CTRL>
__device__ __forceinline__ float qp_bcast(float v) {
    return __int_as_float(__builtin_amdgcn_mov_dpp(__float_as_int(v), CTRL, 0xF, 0xF, true));
}

// Block = 256 threads = TWO batch elements; grid 256 -> 1 block/CU, 4 waves/CU,
// 1 wave/SIMD. Thread (u = tid>>2, s = tid&3): all 4 gates of unit u over
// K-quarter [16s,16s+16) -- only 64 weight floats (r2/r4/r6/r7 lesson: >=128
// always demotes to AGPR, ~1 copy-inst per weight per step). The SAME weight
// registers serve BOTH batches: two independent recurrences interleaved in one
// instruction stream hide each other's LDS latency (in-wave ILP that the
// per-step barrier cannot phase-lock away). Fast activations (exp2+rcp), quad
// butterfly reduce + per-lane activation + quad broadcast, ONE barrier/step.
__global__ __launch_bounds__(256)
__attribute__((amdgpu_waves_per_eu(1, 1)))
void lstm_ar_kernel(
    const float* __restrict__ x,     // [B, 96, 7]
    const float* __restrict__ W_ih,  // [256, 7]
    const float* __restrict__ W_hh,  // [256, 64]
    const float* __restrict__ b_ih,  // [256]
    const float* __restrict__ b_hh,  // [256]
    const float* __restrict__ fc_W,  // [7, 64]
    const float* __restrict__ fc_b,  // [7]
    float* __restrict__ out)         // [B, 16, 7]
{
    __shared__ float xs[2][TL * XSTR];   // per-batch padded timeline (pad = 0)
    __shared__ float hb[2][2][HIDDEN];   // [batch][parity][unit] h ping-pong
    __shared__ float fcw[FEAT * HIDDEN];
    __shared__ float fcb[FEAT];

    const int tid = threadIdx.x;
    const int b0  = blockIdx.x * 2;      // this block's two batches: b0, b0+1
    const int u   = tid >> 2;            // hidden unit 0..63
    const int s   = tid & 3;             // K-quarter / lane-gate role

    // ---- per-thread weights: 4 gates x 16 K-cols as 8 v2f (64 floats) ----
    v2f wh[4][8];
    #pragma unroll
    for (int g = 0; g < 4; ++g) {
        const float* wr = W_hh + (u + (g << 6)) * HIDDEN + (s << 4);
        #pragma unroll
        for (int j = 0; j < 8; ++j) wh[g][j] = *(const v2f*)(wr + 2 * j);
    }
    v2f wx[4];                           // x-cols (2s, 2s+1); col 7 -> 0 (eats pad)
    #pragma unroll
    for (int g = 0; g < 4; ++g) {
        int c0 = (s << 1), c1 = c0 + 1;
        wx[g].x = W_ih[(u + (g << 6)) * FEAT + c0];
        wx[g].y = (c1 < FEAT) ? W_ih[(u + (g << 6)) * FEAT + c1] : 0.0f;
    }
    v2f binit[4];                        // bias carried by s==0 lane only
    #pragma unroll
    for (int g = 0; g < 4; ++g) {
        binit[g].x = (s == 0) ? (b_ih[u + (g << 6)] + b_hh[u + (g << 6)]) : 0.0f;
        binit[g].y = 0.0f;
    }
    // per-lane activation constants (lane s activates gate s; gate 2 = tanh)
    const float actk = (s == 2) ? (-2.0f * L2E) : (-L2E);
    const float actm = (s == 2) ? 2.0f : 1.0f;
    const float actb = (s == 2) ? -1.0f : 0.0f;

    // ---- stage timelines / fc / init ----
    for (int i = tid; i < 2 * TL * XSTR; i += 256) {
        int bloc = i / (TL * XSTR);
        int rem  = i - bloc * (TL * XSTR);
        int row  = rem >> 3, f = rem & 7;
        float v = 0.0f;
        if (row < SEQ_LEN && f < FEAT)
            v = x[(b0 + bloc) * SEQ_LEN * FEAT + row * FEAT + f];
        xs[bloc][rem] = v;
    }
    for (int i = tid; i < FEAT * HIDDEN; i += 256) fcw[i] = fc_W[i];
    if (tid < FEAT) fcb[tid] = fc_b[tid];
    if (tid < 2 * HIDDEN) hb[tid >> 6][0][tid & 63] = 0.0f;
    float c0r = 0.0f, c1r = 0.0f;        // cell states, replicated per quad
    __syncthreads();

    // one step advances BOTH batches, then ONE barrier
    auto step = [&](int row, int pr, int pw) {
        v2f xv0 = *(const v2f*)&xs[0][row * XSTR + (s << 1)];
        v2f xv1 = *(const v2f*)&xs[1][row * XSTR + (s << 1)];
        const float4* h40 = (const float4*)&hb[0][pr][s << 4];
        const float4* h41 = (const float4*)&hb[1][pr][s << 4];

        v2f A0 = binit[0], A1 = binit[1], A2 = binit[2], A3 = binit[3];
        v2f B0 = binit[0], B1 = binit[1], B2 = binit[2], B3 = binit[3];
        A0 = __builtin_elementwise_fma(wx[0], xv0, A0);
        B0 = __builtin_elementwise_fma(wx[0], xv1, B0);
        A1 = __builtin_elementwise_fma(wx[1], xv0, A1);
        B1 = __builtin_elementwise_fma(wx[1], xv1, B1);
        A2 = __builtin_elementwise_fma(wx[2], xv0, A2);
        B2 = __builtin_elementwise_fma(wx[2], xv1, B2);
        A3 = __builtin_elementwise_fma(wx[3], xv0, A3);
        B3 = __builtin_elementwise_fma(wx[3], xv1, B3);

        #pragma unroll
        for (int j = 0; j < 4; ++j) {
            float4 hv0 = h40[j];
            float4 hv1 = h41[j];
            v2f a_lo; a_lo.x = hv0.x; a_lo.y = hv0.y;
            v2f a_hi; a_hi.x = hv0.z; a_hi.y = hv0.w;
            v2f b_lo; b_lo.x = hv1.x; b_lo.y = hv1.y;
            v2f b_hi; b_hi.x = hv1.z; b_hi.y = hv1.w;
            A0 = __builtin_elementwise_fma(wh[0][2*j],   a_lo, A0);
            B0 = __builtin_elementwise_fma(wh[0][2*j],   b_lo, B0);
            A1 = __builtin_elementwise_fma(wh[1][2*j],   a_lo, A1);
            B1 = __builtin_elementwise_fma(wh[1][2*j],   b_lo, B1);
            A2 = __builtin_elementwise_fma(wh[2][2*j],   a_lo, A2);
            B2 = __builtin_elementwise_fma(wh[2][2*j],   b_lo, B2);
            A3 = __builtin_elementwise_fma(wh[3][2*j],   a_lo, A3);
            B3 = __builtin_elementwise_fma(wh[3][2*j],   b_lo, B3);
            A0 = __builtin_elementwise_fma(wh[0][2*j+1], a_hi, A0);
            B0 = __builtin_elementwise_fma(wh[0][2*j+1], b_hi, B0);
            A1 = __builtin_elementwise_fma(wh[1][2*j+1], a_hi, A1);
            B1 = __builtin_elementwise_fma(wh[1][2*j+1], b_hi, B1);
            A2 = __builtin_elementwise_fma(wh[2][2*j+1], a_hi, A2);
            B2 = __builtin_elementwise_fma(wh[2][2*j+1], b_hi, B2);
            A3 = __builtin_elementwise_fma(wh[3][2*j+1], a_hi, A3);
            B3 = __builtin_elementwise_fma(wh[3][2*j+1], b_hi, B3);
        }

        // per-batch: horizontal + quad butterfly + per-lane act + bcast + cell
        float r0 = A0.x + A0.y, r1 = A1.x + A1.y;
        float r2 = A2.x + A2.y, r3 = A3.x + A3.y;
        float q0 = B0.x + B0.y, q1 = B1.x + B1.y;
        float q2 = B2.x + B2.y, q3 = B3.x + B3.y;
        r0 += qp_xor1(r0); r1 += qp_xor1(r1); r2 += qp_xor1(r2); r3 += qp_xor1(r3);
        q0 += qp_xor1(q0); q1 += qp_xor1(q1); q2 += qp_xor1(q2); q3 += qp_xor1(q3);
        r0 += qp_xor2(r0); r1 += qp_xor2(r1); r2 += qp_xor2(r2); r3 += qp_xor2(r3);
        q0 += qp_xor2(q0); q1 += qp_xor2(q1); q2 += qp_xor2(q2); q3 += qp_xor2(q3);

        // lane s activates gate s (branchless select + exp2/rcp)
        float ra_ab = (s & 1) ? r1 : r0;
        float ra_cd = (s & 1) ? r3 : r2;
        float ra    = (s & 2) ? ra_cd : ra_ab;
        float qa_ab = (s & 1) ? q1 : q0;
        float qa_cd = (s & 1) ? q3 : q2;
        float qa    = (s & 2) ? qa_cd : qa_ab;
        float ea  = __builtin_amdgcn_exp2f(ra * actk);
        float eb  = __builtin_amdgcn_exp2f(qa * actk);
        float va  = fmaf(actm, __builtin_amdgcn_rcpf(1.0f + ea), actb);
        float vb  = fmaf(actm, __builtin_amdgcn_rcpf(1.0f + eb), actb);

        // canonical (i,f,g,o) to all quad lanes
        float gi0 = qp_bcast<0x00>(va), gf0 = qp_bcast<0x55>(va);
        float gg0 = qp_bcast<0xAA>(va), go0 = qp_bcast<0xFF>(va);
        float gi1 = qp_bcast<0x00>(vb), gf1 = qp_bcast<0x55>(vb);
        float gg1 = qp_bcast<0xAA>(vb), go1 = qp_bcast<0xFF>(vb);

        c0r = fmaf(gf0, c0r, gi0 * gg0);
        c1r = fmaf(gf1, c1r, gi1 * gg1);
        float t0 = fmaf(2.0f, __builtin_amdgcn_rcpf(
                        1.0f + __builtin_amdgcn_exp2f(c0r * (-2.0f * L2E))), -1.0f);
        float t1 = fmaf(2.0f, __builtin_amdgcn_rcpf(
                        1.0f + __builtin_amdgcn_exp2f(c1r * (-2.0f * L2E))), -1.0f);
        float h0 = go0 * t0;
        float h1 = go1 * t1;

        hb[0][pw][u] = h0;            // 4 lanes, same addr, identical bits
        hb[1][pw][u] = h1;
        __syncthreads();              // the ONLY barrier per step
    };

    for (int k = 0; k < PRED_LEN; ++k) {
        for (int t = 0; t < SEQ_LEN; t += 2) {
            step(k + t,     0, 1);
            step(k + t + 1, 1, 0);
        }
        // after 96 steps latest h is at parity 0

        // ---- prediction heads: wave 0 lanes 0-6 -> batch 0; wave 2 -> batch 1 ----
        const int role = tid >> 7;
        const int l    = tid & 127;
        if (l < FEAT) {
            const float4* hh = (const float4*)hb[role][0];
            float p0 = fcb[l], p1 = 0.0f, p2 = 0.0f, p3 = 0.0f;
            #pragma unroll
            for (int j = 0; j < 16; ++j) {
                float4 hv = hh[j];
                p0 = fmaf(fcw[l * HIDDEN + 4*j + 0], hv.x, p0);
                p1 = fmaf(fcw[l * HIDDEN + 4*j + 1], hv.y, p1);
                p2 = fmaf(fcw[l * HIDDEN + 4*j + 2], hv.z, p2);
                p3 = fmaf(fcw[l * HIDDEN + 4*j + 3], hv.w, p3);
            }
            float pred = (p0 + p1) + (p2 + p3);
            out[((b0 + role) * PRED_LEN + k) * FEAT + l] = pred;
            xs[role][(SEQ_LEN + k) * XSTR + l] = pred;   // append (pad stays 0)
        }
        __syncthreads();
    }
}

extern "C" void kernel_launch(void* const* d_in, const int* in_sizes, int n_in,
                              void* d_out, int out_size, void* d_ws, size_t ws_size,
                              hipStream_t stream) {
    const float* x    = (const float*)d_in[0];
    const float* W_ih = (const float*)d_in[1];
    const float* W_hh = (const float*)d_in[2];
    const float* b_ih = (const float*)d_in[3];
    const float* b_hh = (const float*)d_in[4];
    const float* fc_W = (const float*)d_in[5];
    const float* fc_b = (const float*)d_in[6];
    float* out = (float*)d_out;

    lstm_ar_kernel<<<BATCH / 2, 256, 0, stream>>>(x, W_ih, W_hh, b_ih, b_hh, fc_W, fc_b, out);
}

// Round 9
// 539.744 us; speedup vs baseline: 1.2886x; 1.2886x over previous
//
#include <hip/hip_runtime.h>

#define SEQ_LEN 96
#define PRED_LEN 16
#define HIDDEN 64
#define FEAT 7
#define BATCH 512
#define TL (SEQ_LEN + PRED_LEN)   // 112-row sliding timeline
#define XSTR 8                    // padded row stride

typedef float v2f __attribute__((ext_vector_type(2)));

#define L2E 1.4426950408889634f

// DPP pair-swap (0<->1, 2<->3, ...): quad_perm [1,0,3,2]. Pure VALU.
__device__ __forceinline__ float qp_xor1(float v) {
    return __int_as_float(__builtin_amdgcn_mov_dpp(__float_as_int(v), 0xB1, 0xF, 0xF, true));
}

// r7 structure (best: 567us) + two changes:
//  1. amdgpu_num_vgpr(256): four rounds (r2/r4/r6/r7) prove the allocator
//     caps at 132 arch VGPRs and demotes the 128-float weight set to AGPR,
//     costing ~130 copy-insts/step. Force a 256-VGPR budget (needs ~190;
//     1 wave/SIMD config doesn't care about occupancy).
//  2. Software-pipelined x-prefetch: next step's xs read is issued after the
//     h-write, BEFORE the barrier (fills the barrier shadow). The t=95
//     prefetch reads a future row pre-epilogue (stale, unused, no race).
// Block = 128 threads (2 waves) = ONE batch; grid 512 -> 2 blocks/CU with
// STAGGERED barriers (the r8 lesson: 1 block/CU phase-locks the whole CU).
// Thread (u=tid>>1, s=tid&1): all 4 gates of unit u, K-half [32s,32s+32).
__global__ __launch_bounds__(128)
__attribute__((amdgpu_waves_per_eu(1, 1)))
__attribute__((amdgpu_num_vgpr(256)))
void lstm_ar_kernel(
    const float* __restrict__ x,     // [B, 96, 7]
    const float* __restrict__ W_ih,  // [256, 7]
    const float* __restrict__ W_hh,  // [256, 64]
    const float* __restrict__ b_ih,  // [256]
    const float* __restrict__ b_hh,  // [256]
    const float* __restrict__ fc_W,  // [7, 64]
    const float* __restrict__ fc_b,  // [7]
    float* __restrict__ out)         // [B, 16, 7]
{
    __shared__ float xs[TL * XSTR];   // padded sliding timeline (pad slot = 0)
    __shared__ float hb0[HIDDEN];     // h ping-pong
    __shared__ float hb1[HIDDEN];
    __shared__ float fcw[FEAT * HIDDEN];
    __shared__ float fcb[FEAT];

    const int tid = threadIdx.x;
    const int b   = blockIdx.x;
    const int u   = tid >> 1;         // hidden unit 0..63
    const int s   = tid & 1;          // K-half / activation-role

    // ---- per-thread weights: 4 gates x 32 K-cols as 16 v2f each ----
    v2f wh[4][16];
    #pragma unroll
    for (int g = 0; g < 4; ++g) {
        const float* wr = W_hh + (u + (g << 6)) * HIDDEN + (s << 5);
        #pragma unroll
        for (int j = 0; j < 16; ++j) wh[g][j] = *(const v2f*)(wr + 2 * j);
    }
    v2f wx[4][2];                     // x-cols [4s, 4s+4); col 7 -> 0 (eats pad)
    #pragma unroll
    for (int g = 0; g < 4; ++g)
        #pragma unroll
        for (int i = 0; i < 2; ++i) {
            int c0 = (s << 2) + 2 * i, c1 = c0 + 1;
            wx[g][i].x = W_ih[(u + (g << 6)) * FEAT + c0];
            wx[g][i].y = (c1 < FEAT) ? W_ih[(u + (g << 6)) * FEAT + c1] : 0.0f;
        }
    float bias[4];                    // bias carried by s==0 only
    #pragma unroll
    for (int g = 0; g < 4; ++g)
        bias[g] = (s == 0) ? (b_ih[u + (g << 6)] + b_hh[u + (g << 6)]) : 0.0f;

    // act_b per-lane consts: s=0 -> gate o (sigmoid), s=1 -> gate g (tanh)
    const float bk  = (s == 1) ? (-2.0f * L2E) : (-L2E);
    const float bm  = (s == 1) ? 2.0f : 1.0f;
    const float bbc = (s == 1) ? -1.0f : 0.0f;

    // ---- stage timeline / fc / init ----
    for (int i = tid; i < TL * XSTR; i += 128) {
        int row = i >> 3, f = i & 7;
        float v = 0.0f;
        if (row < SEQ_LEN && f < FEAT) v = x[b * SEQ_LEN * FEAT + row * FEAT + f];
        xs[i] = v;
    }
    for (int i = tid; i < FEAT * HIDDEN; i += 128) fcw[i] = fc_W[i];
    if (tid < FEAT)   fcb[tid] = fc_b[tid];
    if (tid < HIDDEN) hb0[tid] = 0.0f;
    float c = 0.0f;                   // c_u replica (identical in both pair lanes)
    __syncthreads();

    // One step: consumes pre-fetched xv, reads hr, writes hw, prefetches the
    // x row `nrow` AFTER the h-write / BEFORE the barrier, returns it.
    auto step = [&](float4 xv, int nrow,
                    const float* __restrict__ hr, float* __restrict__ hw) -> float4 {
        const float4* h4 = (const float4*)(hr + (s << 5));

        v2f A0, A1, A2, A3;
        A0.x = bias[0]; A0.y = 0.0f;
        A1.x = bias[1]; A1.y = 0.0f;
        A2.x = bias[2]; A2.y = 0.0f;
        A3.x = bias[3]; A3.y = 0.0f;
        v2f xlo; xlo.x = xv.x; xlo.y = xv.y;
        v2f xhi; xhi.x = xv.z; xhi.y = xv.w;
        A0 = __builtin_elementwise_fma(wx[0][0], xlo, A0);
        A1 = __builtin_elementwise_fma(wx[1][0], xlo, A1);
        A2 = __builtin_elementwise_fma(wx[2][0], xlo, A2);
        A3 = __builtin_elementwise_fma(wx[3][0], xlo, A3);
        A0 = __builtin_elementwise_fma(wx[0][1], xhi, A0);
        A1 = __builtin_elementwise_fma(wx[1][1], xhi, A1);
        A2 = __builtin_elementwise_fma(wx[2][1], xhi, A2);
        A3 = __builtin_elementwise_fma(wx[3][1], xhi, A3);

        #pragma unroll
        for (int j = 0; j < 8; ++j) {
            float4 hv = h4[j];
            v2f hlo; hlo.x = hv.x; hlo.y = hv.y;
            v2f hhi; hhi.x = hv.z; hhi.y = hv.w;
            A0 = __builtin_elementwise_fma(wh[0][2*j],   hlo, A0);
            A1 = __builtin_elementwise_fma(wh[1][2*j],   hlo, A1);
            A2 = __builtin_elementwise_fma(wh[2][2*j],   hlo, A2);
            A3 = __builtin_elementwise_fma(wh[3][2*j],   hlo, A3);
            A0 = __builtin_elementwise_fma(wh[0][2*j+1], hhi, A0);
            A1 = __builtin_elementwise_fma(wh[1][2*j+1], hhi, A1);
            A2 = __builtin_elementwise_fma(wh[2][2*j+1], hhi, A2);
            A3 = __builtin_elementwise_fma(wh[3][2*j+1], hhi, A3);
        }

        // horizontal + ONE pair-reduce round: both lanes get all 4 gate sums
        float r0 = A0.x + A0.y, r1 = A1.x + A1.y;
        float r2 = A2.x + A2.y, r3 = A3.x + A3.y;
        r0 += qp_xor1(r0); r1 += qp_xor1(r1);
        r2 += qp_xor1(r2); r3 += qp_xor1(r3);

        // lane roles: s=0 activates f(r1),o(r3); s=1 activates i(r0),g(r2)
        float aa = s ? r0 : r1;                       // sigmoid in both lanes
        float ab = s ? r2 : r3;                       // tanh | sigmoid
        float ea = __builtin_amdgcn_exp2f(aa * (-L2E));
        float va = __builtin_amdgcn_rcpf(1.0f + ea);  // sigmoid(aa)
        float eb = __builtin_amdgcn_exp2f(ab * bk);
        float rb = __builtin_amdgcn_rcpf(1.0f + eb);
        float vb = fmaf(bm, rb, bbc);

        // exchange with partner lane, canonicalize (i,f,g,o)
        float pa = qp_xor1(va);
        float pb = qp_xor1(vb);
        float gi = s ? va : pa;
        float gf = s ? pa : va;
        float gg = s ? vb : pb;
        float go = s ? pb : vb;

        c = fmaf(gf, c, gi * gg);
        float e2 = __builtin_amdgcn_exp2f(c * (-2.0f * L2E));
        float rr = __builtin_amdgcn_rcpf(1.0f + e2);
        float th = fmaf(2.0f, rr, -1.0f);             // tanh(c)
        float h  = go * th;

        hw[u] = h;                  // both pair lanes: same addr, identical bits

        // prefetch next x row in the barrier shadow (independent of h)
        float4 nxt = *(const float4*)&xs[nrow * XSTR + (s << 2)];
        __syncthreads();            // the ONLY barrier per step
        return nxt;
    };

    for (int k = 0; k < PRED_LEN; ++k) {
        float4 xv = *(const float4*)&xs[k * XSTR + (s << 2)];   // row k (t=0)
        for (int t = 0; t < SEQ_LEN; t += 2) {
            xv = step(xv, k + t + 1, hb0, hb1);
            xv = step(xv, k + t + 2, hb1, hb0);   // t=94: prefetch row k+96 (<112, discarded)
        }
        // after 96 steps the latest h is in hb0

        // ---- prediction head: lanes 0..6 of wave 0 ----
        if (tid < FEAT) {
            float p0 = fcb[tid], p1 = 0.0f, p2 = 0.0f, p3 = 0.0f;
            const float4* hh = (const float4*)hb0;
            #pragma unroll
            for (int j = 0; j < 16; ++j) {
                float4 hv = hh[j];
                p0 = fmaf(fcw[tid * HIDDEN + 4*j + 0], hv.x, p0);
                p1 = fmaf(fcw[tid * HIDDEN + 4*j + 1], hv.y, p1);
                p2 = fmaf(fcw[tid * HIDDEN + 4*j + 2], hv.z, p2);
                p3 = fmaf(fcw[tid * HIDDEN + 4*j + 3], hv.w, p3);
            }
            float pred = (p0 + p1) + (p2 + p3);
            out[(b * PRED_LEN + k) * FEAT + tid] = pred;
            xs[(SEQ_LEN + k) * XSTR + tid] = pred;   // append (pad slot stays 0)
        }
        __syncthreads();
    }
}

extern "C" void kernel_launch(void* const* d_in, const int* in_sizes, int n_in,
                              void* d_out, int out_size, void* d_ws, size_t ws_size,
                              hipStream_t stream) {
    const float* x    = (const float*)d_in[0];
    const float* W_ih = (const float*)d_in[1];
    const float* W_hh = (const float*)d_in[2];
    const float* b_ih = (const float*)d_in[3];
    const float* b_hh = (const float*)d_in[4];
    const float* fc_W = (const float*)d_in[5];
    const float* fc_b = (const float*)d_in[6];
    float* out = (float*)d_out;

    lstm_ar_kernel<<<BATCH, 128, 0, stream>>>(x, W_ih, W_hh, b_ih, b_hh, fc_W, fc_b, out);
}